// Round 2
// baseline (673.482 us; speedup 1.0000x reference)
//
#include <hip/hip_runtime.h>
#include <hip/hip_bf16.h>

// FusionRetrModel: B=4, NL=2 (only l=1 used), P=100, TOK=60, T=6000, D=768.
// R2 pipeline:
//   prep: Qpad bf16 [4][6016][768]; Bcat[b]=[Wpb;Wtb] bf16 [4][1536][768];
//         cp/ct[b][d] = A@W1^T + bias; Wf1 cast bf16; out init = bf2*msum.
//   gemm12: [ps|ts] = Qpad @ Bcat^T + [cp|ct]  (one N=1536 MFMA GEMM)
//   tmax:   per-table elementwise max over passages (from ts)
//   gemm3s: H = [ps | tmax-indirect] @ Wf1^T  (K=1536), epilogue computes
//           relu(H+bf1)@w2, reduces over cols, atomicAdd mask-weighted into out.
// Workspace: 126,394,368 bytes.

typedef unsigned short u16;
typedef unsigned int u32;
typedef __attribute__((ext_vector_type(8))) short bf16x8;
typedef __attribute__((ext_vector_type(4))) float f32x4;

#define NUM_TABLES 10
#define MPAD 6016
#define DD 768

__device__ __forceinline__ u16 f2bf(float f) {
  u32 u = __builtin_bit_cast(u32, f);
  u32 r = u + 0x7FFFu + ((u >> 16) & 1u);
  return (u16)(r >> 16);
}
__device__ __forceinline__ float bf2f(u16 h) {
  u32 u = ((u32)h) << 16;
  return __builtin_bit_cast(float, u);
}

__device__ __forceinline__ void gload_lds16(const u16* g, u16* l) {
  __builtin_amdgcn_global_load_lds(
      (const __attribute__((address_space(1))) void*)g,
      (__attribute__((address_space(3))) void*)l, 16, 0, 0);
}

// ---------------- prep kernels ----------------

// cast Q (l=1 slice) to bf16, pad rows [6000,6016) with zeros. 8 elems/thread.
__global__ void prep_q(const float* __restrict__ qps, uint4* __restrict__ qpad) {
  size_t c = (size_t)blockIdx.x * 256 + threadIdx.x;
  const int per_b = MPAD * (DD / 8);
  if (c >= (size_t)4 * per_b) return;
  int b = (int)(c / per_b);
  int rr = (int)(c % per_b);
  int r = rr / (DD / 8);
  int kc = rr % (DD / 8);
  uint4 o;
  if (r < 6000) {
    const float* src = qps + (((size_t)(b * 2 + 1)) * 6000 + r) * DD + kc * 8;
    float4 f0 = *(const float4*)src;
    float4 f1 = *(const float4*)(src + 4);
    o.x = (u32)f2bf(f0.x) | ((u32)f2bf(f0.y) << 16);
    o.y = (u32)f2bf(f0.z) | ((u32)f2bf(f0.w) << 16);
    o.z = (u32)f2bf(f1.x) | ((u32)f2bf(f1.y) << 16);
    o.w = (u32)f2bf(f1.z) | ((u32)f2bf(f1.w) << 16);
  } else {
    o = make_uint4(0, 0, 0, 0);
  }
  qpad[c] = o;
}

// Bcat[b][d][k] = Wp[d][768+k] + A[b][k]*Wp[d][1536+k]  (rows 0..767)
// Bcat[b][768+d][k] = same from Wt                      (rows 768..1535)
__global__ void prep_wcomb(const float* __restrict__ Ans, const float* __restrict__ Wp,
                           const float* __restrict__ Wt, u16* __restrict__ Bcat) {
  size_t c = (size_t)blockIdx.x * 256 + threadIdx.x;
  const int per_b = DD * (DD / 4);
  if (c >= (size_t)4 * per_b) return;
  int b = (int)(c / per_b);
  int rr = (int)(c % per_b);
  int d = rr / (DD / 4);
  int k4 = (rr % (DD / 4)) * 4;
  float4 av = *(const float4*)(Ans + ((size_t)b * 2 + 1) * DD + k4);
  float4 p2 = *(const float4*)(Wp + (size_t)d * 2304 + 768 + k4);
  float4 p3 = *(const float4*)(Wp + (size_t)d * 2304 + 1536 + k4);
  float4 t2 = *(const float4*)(Wt + (size_t)d * 2304 + 768 + k4);
  float4 t3 = *(const float4*)(Wt + (size_t)d * 2304 + 1536 + k4);
  uint2 op, ot;
  op.x = (u32)f2bf(p2.x + av.x * p3.x) | ((u32)f2bf(p2.y + av.y * p3.y) << 16);
  op.y = (u32)f2bf(p2.z + av.z * p3.z) | ((u32)f2bf(p2.w + av.w * p3.w) << 16);
  ot.x = (u32)f2bf(t2.x + av.x * t3.x) | ((u32)f2bf(t2.y + av.y * t3.y) << 16);
  ot.y = (u32)f2bf(t2.z + av.z * t3.z) | ((u32)f2bf(t2.w + av.w * t3.w) << 16);
  size_t ip = ((size_t)b * 1536 + d) * DD + k4;
  size_t it = ((size_t)b * 1536 + 768 + d) * DD + k4;
  *(uint2*)(Bcat + ip) = op;
  *(uint2*)(Bcat + it) = ot;
}

// cp[b][d] = sum_k A[b][k]*Wp[d][k] + bp[d]; ct likewise.
__global__ void prep_consts(const float* __restrict__ Ans, const float* __restrict__ Wp,
                            const float* __restrict__ bp, const float* __restrict__ Wt,
                            const float* __restrict__ bt,
                            float* __restrict__ cp, float* __restrict__ ct) {
  int idx = blockIdx.x * 256 + threadIdx.x;
  if (idx >= 4 * DD) return;
  int b = idx / DD, d = idx % DD;
  const float* a = Ans + ((size_t)b * 2 + 1) * DD;
  const float* wp = Wp + (size_t)d * 2304;
  const float* wt = Wt + (size_t)d * 2304;
  float sp = 0.f, st = 0.f;
  for (int k = 0; k < DD; k += 4) {
    float4 av = *(const float4*)(a + k);
    float4 pv = *(const float4*)(wp + k);
    float4 tv = *(const float4*)(wt + k);
    sp += av.x * pv.x + av.y * pv.y + av.z * pv.z + av.w * pv.w;
    st += av.x * tv.x + av.y * tv.y + av.z * tv.z + av.w * tv.w;
  }
  cp[idx] = sp + bp[d];
  ct[idx] = st + bt[d];
}

// cast Wf1 [768][1536] to bf16 (same layout). 8 elems/thread.
__global__ void prep_wf1(const float* __restrict__ Wf1, uint4* __restrict__ Wf1b) {
  size_t c = (size_t)blockIdx.x * 256 + threadIdx.x;
  if (c >= (size_t)DD * 1536 / 8) return;
  const float* src = Wf1 + c * 8;
  float4 f0 = *(const float4*)src;
  float4 f1 = *(const float4*)(src + 4);
  uint4 o;
  o.x = (u32)f2bf(f0.x) | ((u32)f2bf(f0.y) << 16);
  o.y = (u32)f2bf(f0.z) | ((u32)f2bf(f0.w) << 16);
  o.z = (u32)f2bf(f1.x) | ((u32)f2bf(f1.y) << 16);
  o.w = (u32)f2bf(f1.z) | ((u32)f2bf(f1.w) << 16);
  Wf1b[c] = o;
}

// out[b,p] = bf2[0] * sum_tok mask[b,p,tok]   (atomic-add target init)
__global__ void init_out(const float* __restrict__ mask, const float* __restrict__ bf2,
                         float* __restrict__ out) {
  int idx = blockIdx.x * 256 + threadIdx.x;
  if (idx >= 400) return;
  const float* m = mask + (size_t)idx * 60;
  float s = 0.f;
  for (int t = 0; t < 60; ++t) s += m[t];
  out[idx] = bf2[0] * s;
}

// ---------------- gemm12: [ps|ts] = Qpad @ Bcat^T + [cp|ct] ----------------
// 128x128 tile, BK=64, 4 waves 2x2. Grid 2256 flat, XCD-chunked, n-fastest.
__global__ __launch_bounds__(256, 2)
void gemm12(const u16* __restrict__ Q, const u16* __restrict__ Bcat,
            const float* __restrict__ cp, const float* __restrict__ ct,
            u16* __restrict__ ps, u16* __restrict__ ts) {
  // flat -> lid: 2256 = 8 * 282
  int flat = blockIdx.x;
  int lid = (flat & 7) * 282 + (flat >> 3);
  int n = lid % 12;
  int m = (lid / 12) % 47;
  int b = lid / 564;

  const int m0 = m * 128;
  const int n0 = n * 128;
  const int tid = threadIdx.x;
  const int lane = tid & 63;
  const int wid = tid >> 6;
  const int wm = wid >> 1, wn = wid & 1;

  __shared__ u16 As[128 * 64];
  __shared__ u16 Bs[128 * 64];

  const u16* Abase = Q + (size_t)b * MPAD * DD;
  const u16* Bbase = Bcat + (size_t)b * 1536 * DD;

  f32x4 acc[4][4] = {};

  const int lrow = lane >> 3;
  const int lcol = (lane & 7) * 8;

  for (int kt = 0; kt < DD / 64; ++kt) {
    const int k0 = kt * 64;
#pragma unroll
    for (int j = 0; j < 4; ++j) {
      const u16* g = Abase + (size_t)(m0 + wid * 32 + j * 8 + lrow) * DD + k0 + lcol;
      gload_lds16(g, &As[(wid * 32 + j * 8) * 64]);
    }
#pragma unroll
    for (int j = 0; j < 4; ++j) {
      const u16* g = Bbase + (size_t)(n0 + wid * 32 + j * 8 + lrow) * DD + k0 + lcol;
      gload_lds16(g, &Bs[(wid * 32 + j * 8) * 64]);
    }
    __syncthreads();

    bf16x8 af[2][4], bfr[2][4];
#pragma unroll
    for (int kf = 0; kf < 2; ++kf)
#pragma unroll
      for (int mf = 0; mf < 4; ++mf)
        af[kf][mf] = *(const bf16x8*)&As[(wm * 64 + mf * 16 + (lane & 15)) * 64 + kf * 32 + (lane >> 4) * 8];
#pragma unroll
    for (int kf = 0; kf < 2; ++kf)
#pragma unroll
      for (int nf = 0; nf < 4; ++nf)
        bfr[kf][nf] = *(const bf16x8*)&Bs[(wn * 64 + nf * 16 + (lane & 15)) * 64 + kf * 32 + (lane >> 4) * 8];

#pragma unroll
    for (int mf = 0; mf < 4; ++mf)
#pragma unroll
      for (int nf = 0; nf < 4; ++nf) {
        acc[mf][nf] = __builtin_amdgcn_mfma_f32_16x16x32_bf16(af[0][mf], bfr[0][nf], acc[mf][nf], 0, 0, 0);
        acc[mf][nf] = __builtin_amdgcn_mfma_f32_16x16x32_bf16(af[1][mf], bfr[1][nf], acc[mf][nf], 0, 0, 0);
      }
    __syncthreads();
  }

  // n0 uniform per block: first half -> ps(+cp), second half -> ts(+ct)
  u16* dst = (n0 < 768 ? ps : ts) + (size_t)b * MPAD * DD;
  const float* cv = (n0 < 768 ? cp : ct) + b * DD;
  const int ncol0 = n0 - (n0 < 768 ? 0 : 768);
#pragma unroll
  for (int mf = 0; mf < 4; ++mf)
#pragma unroll
    for (int nf = 0; nf < 4; ++nf)
#pragma unroll
      for (int r = 0; r < 4; ++r) {
        int row = m0 + wm * 64 + mf * 16 + (lane >> 4) * 4 + r;
        int col = ncol0 + wn * 64 + nf * 16 + (lane & 15);
        dst[(size_t)row * DD + col] = f2bf(acc[mf][nf][r] + cv[col]);
      }
}

// ---------------- table max ----------------
// tmax[b][t][tok][d] = max over p with ids[b][p]==t of ts[b][p*60+tok][d]
__global__ void table_max_kernel(const u16* __restrict__ ts, const int* __restrict__ ids,
                                 u16* __restrict__ tmax) {
  int bi = blockIdx.x;  // 4*60*3 = 720
  int b = bi / 180;
  int rem = bi % 180;
  int tok = rem / 3;
  int dc = rem % 3;
  int d = dc * 256 + threadIdx.x;
  __shared__ int sids[100];
  if (threadIdx.x < 100) sids[threadIdx.x] = ids[b * 100 + threadIdx.x];
  __syncthreads();
  float m[NUM_TABLES];
#pragma unroll
  for (int t = 0; t < NUM_TABLES; ++t) m[t] = -INFINITY;
  const u16* base = ts + ((size_t)b * MPAD + tok) * DD + d;
  for (int p = 0; p < 100; ++p) {
    float v = bf2f(base[(size_t)p * 60 * DD]);
    int id = sids[p];
#pragma unroll
    for (int t = 0; t < NUM_TABLES; ++t)
      if (id == t) m[t] = fmaxf(m[t], v);
  }
#pragma unroll
  for (int t = 0; t < NUM_TABLES; ++t)
    tmax[(((size_t)b * NUM_TABLES + t) * 60 + tok) * DD + d] = f2bf(m[t]);
}

// ---------------- gemm3 + fused score ----------------
// H(row,col) = sum_k [ps | tmax-gather](row,k) * Wf1b(col,k); epilogue:
// s(row) = sum_col relu(H+bf1[col])*w2[col]; atomicAdd(out[b,p], mask*s)
__global__ __launch_bounds__(256, 2)
void gemm3s(const u16* __restrict__ ps, const u16* __restrict__ tmax,
            const int* __restrict__ ids, const u16* __restrict__ Wf1b,
            const float* __restrict__ bf1, const float* __restrict__ w2,
            const float* __restrict__ mask, float* __restrict__ out) {
  // flat -> lid: 1128 = 8 * 141
  int flat = blockIdx.x;
  int lid = (flat & 7) * 141 + (flat >> 3);
  int n = lid % 6;
  int m = (lid / 6) % 47;
  int b = lid / 282;

  const int m0 = m * 128;
  const int n0 = n * 128;
  const int tid = threadIdx.x;
  const int lane = tid & 63;
  const int wid = tid >> 6;
  const int wm = wid >> 1, wn = wid & 1;

  __shared__ u16 As[128 * 64];
  __shared__ u16 Bs[128 * 64];
  __shared__ int sids[100];
  if (tid < 100) sids[tid] = ids[b * 100 + tid];

  const u16* Abase = ps + (size_t)b * MPAD * DD;
  const u16* Tbase = tmax + (size_t)b * NUM_TABLES * 60 * DD;

  f32x4 acc[4][4] = {};

  const int lrow = lane >> 3;
  const int lcol = (lane & 7) * 8;

  for (int kt = 0; kt < 1536 / 64; ++kt) {
    const int k0 = kt * 64;
#pragma unroll
    for (int j = 0; j < 4; ++j) {
      const int row = m0 + wid * 32 + j * 8 + lrow;
      const u16* g;
      if (k0 < 768) {
        g = Abase + (size_t)row * DD + k0 + lcol;
      } else {
        int rp = row < 6000 ? row : 5999;
        int p = (unsigned)rp / 60u;
        int tok = rp - p * 60;
        int id = sids[p];
        g = Tbase + ((size_t)(id * 60 + tok)) * DD + (k0 - 768) + lcol;
      }
      gload_lds16(g, &As[(wid * 32 + j * 8) * 64]);
    }
#pragma unroll
    for (int j = 0; j < 4; ++j) {
      const u16* g = Wf1b + (size_t)(n0 + wid * 32 + j * 8 + lrow) * 1536 + k0 + lcol;
      gload_lds16(g, &Bs[(wid * 32 + j * 8) * 64]);
    }
    __syncthreads();

    bf16x8 af[2][4], bfr[2][4];
#pragma unroll
    for (int kf = 0; kf < 2; ++kf)
#pragma unroll
      for (int mf = 0; mf < 4; ++mf)
        af[kf][mf] = *(const bf16x8*)&As[(wm * 64 + mf * 16 + (lane & 15)) * 64 + kf * 32 + (lane >> 4) * 8];
#pragma unroll
    for (int kf = 0; kf < 2; ++kf)
#pragma unroll
      for (int nf = 0; nf < 4; ++nf)
        bfr[kf][nf] = *(const bf16x8*)&Bs[(wn * 64 + nf * 16 + (lane & 15)) * 64 + kf * 32 + (lane >> 4) * 8];

#pragma unroll
    for (int mf = 0; mf < 4; ++mf)
#pragma unroll
      for (int nf = 0; nf < 4; ++nf) {
        acc[mf][nf] = __builtin_amdgcn_mfma_f32_16x16x32_bf16(af[0][mf], bfr[0][nf], acc[mf][nf], 0, 0, 0);
        acc[mf][nf] = __builtin_amdgcn_mfma_f32_16x16x32_bf16(af[1][mf], bfr[1][nf], acc[mf][nf], 0, 0, 0);
      }
    __syncthreads();
  }

  // fused score epilogue
  float b1v[4], w2v[4];
#pragma unroll
  for (int nf = 0; nf < 4; ++nf) {
    int c = n0 + wn * 64 + nf * 16 + (lane & 15);
    b1v[nf] = bf1[c];
    w2v[nf] = w2[c];
  }
#pragma unroll
  for (int mf = 0; mf < 4; ++mf)
#pragma unroll
    for (int r = 0; r < 4; ++r) {
      int row = m0 + wm * 64 + mf * 16 + (lane >> 4) * 4 + r;
      float s = 0.f;
#pragma unroll
      for (int nf = 0; nf < 4; ++nf)
        s += fmaxf(acc[mf][nf][r] + b1v[nf], 0.f) * w2v[nf];
      s += __shfl_xor(s, 1);
      s += __shfl_xor(s, 2);
      s += __shfl_xor(s, 4);
      s += __shfl_xor(s, 8);
      if ((lane & 15) == 0) {
        int p = (unsigned)row / 60u;
        if (p < 100) {
          int tok = row - p * 60;
          float mk = mask[((size_t)b * 100 + p) * 60 + tok];
          atomicAdd(out + b * 100 + p, mk * s);
        }
      }
    }
}

// ---------------- launch ----------------
extern "C" void kernel_launch(void* const* d_in, const int* in_sizes, int n_in,
                              void* d_out, int out_size, void* d_ws, size_t ws_size,
                              hipStream_t stream) {
  const float* answer = (const float*)d_in[0];
  const float* qps    = (const float*)d_in[1];
  const float* mask   = (const float*)d_in[2];
  const int*   tids   = (const int*)d_in[3];
  const float* Wp     = (const float*)d_in[4];
  const float* bp     = (const float*)d_in[5];
  const float* Wt     = (const float*)d_in[6];
  const float* bt     = (const float*)d_in[7];
  const float* Wf1    = (const float*)d_in[8];
  const float* bf1    = (const float*)d_in[9];
  const float* Wf2    = (const float*)d_in[10];
  const float* bf2    = (const float*)d_in[11];
  float* out = (float*)d_out;

  char* ws = (char*)d_ws;
  // region layout (bytes); total 126,394,368
  u16* Qpad = (u16*)(ws + 0);            // 36,962,304
  u16* ps   = (u16*)(ws + 36962304);     // 36,962,304
  u16* ts   = (u16*)(ws + 73924608);     // 36,962,304
  u16* Bcat = (u16*)(ws + 110886912);    // 9,437,184
  u16* Wf1b = (u16*)(ws + 120324096);    // 2,359,296
  float* cp = (float*)(ws + 122683392);  // 12,288
  float* ct = (float*)(ws + 122695680);  // 12,288
  u16* tmax = (u16*)(ws + 122707968);    // 3,686,400

  init_out<<<2, 256, 0, stream>>>(mask, bf2, out);
  prep_q<<<9024, 256, 0, stream>>>(qps, (uint4*)Qpad);
  prep_wcomb<<<2304, 256, 0, stream>>>(answer, Wp, Wt, Bcat);
  prep_consts<<<12, 256, 0, stream>>>(answer, Wp, bp, Wt, bt, cp, ct);
  prep_wf1<<<576, 256, 0, stream>>>(Wf1, (uint4*)Wf1b);

  // [ps|ts] = Qpad @ Bcat^T + [cp|ct]
  gemm12<<<2256, 256, 0, stream>>>(Qpad, Bcat, cp, ct, ps, ts);

  table_max_kernel<<<720, 256, 0, stream>>>(ts, tids, tmax);

  // H = [ps | tmax-gather] @ Wf1^T, fused relu/w2/mask/score
  gemm3s<<<1128, 256, 0, stream>>>(ps, tmax, tids, Wf1b, bf1, Wf2, mask, out);
}

// Round 3
// 308.403 us; speedup vs baseline: 2.1838x; 2.1838x over previous
//
#include <hip/hip_runtime.h>
#include <hip/hip_bf16.h>

// FusionRetrModel: B=4, NL=2 (only l=1 used), P=100, TOK=60, T=6000, D=768.
// R3 pipeline:
//   prep: Qpad bf16 [4][6016][768]; Bcat[b]=[Wpb;Wtb] bf16 [4][1536][768];
//         cp/ct[b][d] = A@W1^T + bias; Wf1 cast bf16; out init = bf2*msum.
//   gemm12: [ps|ts] = Qpad @ Bcat^T + [cp|ct]  (one N=1536 MFMA GEMM)
//   tmax:   per-table elementwise max over passages (from ts)
//   gemm3s: H = [ps | tmax-indirect] @ Wf1^T  (K=1536), all staging pointers
//           precomputed in VGPRs (no per-iter sids/idiv), two branch-free
//           K-phases; epilogue reduces relu(H+bf1)@w2 into LDS per-passage
//           slots, then <=3 global atomics per block.
// Workspace: 126,394,368 bytes.

typedef unsigned short u16;
typedef unsigned int u32;
typedef __attribute__((ext_vector_type(8))) short bf16x8;
typedef __attribute__((ext_vector_type(4))) float f32x4;

#define NUM_TABLES 10
#define MPAD 6016
#define DD 768

__device__ __forceinline__ u16 f2bf(float f) {
  u32 u = __builtin_bit_cast(u32, f);
  u32 r = u + 0x7FFFu + ((u >> 16) & 1u);
  return (u16)(r >> 16);
}
__device__ __forceinline__ float bf2f(u16 h) {
  u32 u = ((u32)h) << 16;
  return __builtin_bit_cast(float, u);
}

__device__ __forceinline__ void gload_lds16(const u16* g, u16* l) {
  __builtin_amdgcn_global_load_lds(
      (const __attribute__((address_space(1))) void*)g,
      (__attribute__((address_space(3))) void*)l, 16, 0, 0);
}

// ---------------- prep kernels ----------------

__global__ void prep_q(const float* __restrict__ qps, uint4* __restrict__ qpad) {
  size_t c = (size_t)blockIdx.x * 256 + threadIdx.x;
  const int per_b = MPAD * (DD / 8);
  if (c >= (size_t)4 * per_b) return;
  int b = (int)(c / per_b);
  int rr = (int)(c % per_b);
  int r = rr / (DD / 8);
  int kc = rr % (DD / 8);
  uint4 o;
  if (r < 6000) {
    const float* src = qps + (((size_t)(b * 2 + 1)) * 6000 + r) * DD + kc * 8;
    float4 f0 = *(const float4*)src;
    float4 f1 = *(const float4*)(src + 4);
    o.x = (u32)f2bf(f0.x) | ((u32)f2bf(f0.y) << 16);
    o.y = (u32)f2bf(f0.z) | ((u32)f2bf(f0.w) << 16);
    o.z = (u32)f2bf(f1.x) | ((u32)f2bf(f1.y) << 16);
    o.w = (u32)f2bf(f1.z) | ((u32)f2bf(f1.w) << 16);
  } else {
    o = make_uint4(0, 0, 0, 0);
  }
  qpad[c] = o;
}

__global__ void prep_wcomb(const float* __restrict__ Ans, const float* __restrict__ Wp,
                           const float* __restrict__ Wt, u16* __restrict__ Bcat) {
  size_t c = (size_t)blockIdx.x * 256 + threadIdx.x;
  const int per_b = DD * (DD / 4);
  if (c >= (size_t)4 * per_b) return;
  int b = (int)(c / per_b);
  int rr = (int)(c % per_b);
  int d = rr / (DD / 4);
  int k4 = (rr % (DD / 4)) * 4;
  float4 av = *(const float4*)(Ans + ((size_t)b * 2 + 1) * DD + k4);
  float4 p2 = *(const float4*)(Wp + (size_t)d * 2304 + 768 + k4);
  float4 p3 = *(const float4*)(Wp + (size_t)d * 2304 + 1536 + k4);
  float4 t2 = *(const float4*)(Wt + (size_t)d * 2304 + 768 + k4);
  float4 t3 = *(const float4*)(Wt + (size_t)d * 2304 + 1536 + k4);
  uint2 op, ot;
  op.x = (u32)f2bf(p2.x + av.x * p3.x) | ((u32)f2bf(p2.y + av.y * p3.y) << 16);
  op.y = (u32)f2bf(p2.z + av.z * p3.z) | ((u32)f2bf(p2.w + av.w * p3.w) << 16);
  ot.x = (u32)f2bf(t2.x + av.x * t3.x) | ((u32)f2bf(t2.y + av.y * t3.y) << 16);
  ot.y = (u32)f2bf(t2.z + av.z * t3.z) | ((u32)f2bf(t2.w + av.w * t3.w) << 16);
  size_t ip = ((size_t)b * 1536 + d) * DD + k4;
  size_t it = ((size_t)b * 1536 + 768 + d) * DD + k4;
  *(uint2*)(Bcat + ip) = op;
  *(uint2*)(Bcat + it) = ot;
}

__global__ void prep_consts(const float* __restrict__ Ans, const float* __restrict__ Wp,
                            const float* __restrict__ bp, const float* __restrict__ Wt,
                            const float* __restrict__ bt,
                            float* __restrict__ cp, float* __restrict__ ct) {
  int idx = blockIdx.x * 256 + threadIdx.x;
  if (idx >= 4 * DD) return;
  int b = idx / DD, d = idx % DD;
  const float* a = Ans + ((size_t)b * 2 + 1) * DD;
  const float* wp = Wp + (size_t)d * 2304;
  const float* wt = Wt + (size_t)d * 2304;
  float sp = 0.f, st = 0.f;
  for (int k = 0; k < DD; k += 4) {
    float4 av = *(const float4*)(a + k);
    float4 pv = *(const float4*)(wp + k);
    float4 tv = *(const float4*)(wt + k);
    sp += av.x * pv.x + av.y * pv.y + av.z * pv.z + av.w * pv.w;
    st += av.x * tv.x + av.y * tv.y + av.z * tv.z + av.w * tv.w;
  }
  cp[idx] = sp + bp[d];
  ct[idx] = st + bt[d];
}

__global__ void prep_wf1(const float* __restrict__ Wf1, uint4* __restrict__ Wf1b) {
  size_t c = (size_t)blockIdx.x * 256 + threadIdx.x;
  if (c >= (size_t)DD * 1536 / 8) return;
  const float* src = Wf1 + c * 8;
  float4 f0 = *(const float4*)src;
  float4 f1 = *(const float4*)(src + 4);
  uint4 o;
  o.x = (u32)f2bf(f0.x) | ((u32)f2bf(f0.y) << 16);
  o.y = (u32)f2bf(f0.z) | ((u32)f2bf(f0.w) << 16);
  o.z = (u32)f2bf(f1.x) | ((u32)f2bf(f1.y) << 16);
  o.w = (u32)f2bf(f1.z) | ((u32)f2bf(f1.w) << 16);
  Wf1b[c] = o;
}

__global__ void init_out(const float* __restrict__ mask, const float* __restrict__ bf2,
                         float* __restrict__ out) {
  int idx = blockIdx.x * 256 + threadIdx.x;
  if (idx >= 400) return;
  const float* m = mask + (size_t)idx * 60;
  float s = 0.f;
  for (int t = 0; t < 60; ++t) s += m[t];
  out[idx] = bf2[0] * s;
}

// ---------------- gemm12: [ps|ts] = Qpad @ Bcat^T + [cp|ct] ----------------
__global__ __launch_bounds__(256, 2)
void gemm12(const u16* __restrict__ Q, const u16* __restrict__ Bcat,
            const float* __restrict__ cp, const float* __restrict__ ct,
            u16* __restrict__ ps, u16* __restrict__ ts) {
  int flat = blockIdx.x;
  int lid = (flat & 7) * 282 + (flat >> 3);
  int n = lid % 12;
  int m = (lid / 12) % 47;
  int b = lid / 564;

  const int m0 = m * 128;
  const int n0 = n * 128;
  const int tid = threadIdx.x;
  const int lane = tid & 63;
  const int wid = tid >> 6;
  const int wm = wid >> 1, wn = wid & 1;

  __shared__ u16 As[128 * 64];
  __shared__ u16 Bs[128 * 64];

  const u16* Abase = Q + (size_t)b * MPAD * DD;
  const u16* Bbase = Bcat + (size_t)b * 1536 * DD;

  f32x4 acc[4][4] = {};

  const int lrow = lane >> 3;
  const int lcol = (lane & 7) * 8;

  const u16* aptr[4];
  const u16* bptr[4];
#pragma unroll
  for (int j = 0; j < 4; ++j) {
    aptr[j] = Abase + (size_t)(m0 + wid * 32 + j * 8 + lrow) * DD + lcol;
    bptr[j] = Bbase + (size_t)(n0 + wid * 32 + j * 8 + lrow) * DD + lcol;
  }

  for (int kt = 0; kt < DD / 64; ++kt) {
#pragma unroll
    for (int j = 0; j < 4; ++j) gload_lds16(aptr[j], &As[(wid * 32 + j * 8) * 64]);
#pragma unroll
    for (int j = 0; j < 4; ++j) gload_lds16(bptr[j], &Bs[(wid * 32 + j * 8) * 64]);
#pragma unroll
    for (int j = 0; j < 4; ++j) { aptr[j] += 64; bptr[j] += 64; }
    __syncthreads();

    bf16x8 af[2][4], bfr[2][4];
#pragma unroll
    for (int kf = 0; kf < 2; ++kf)
#pragma unroll
      for (int mf = 0; mf < 4; ++mf)
        af[kf][mf] = *(const bf16x8*)&As[(wm * 64 + mf * 16 + (lane & 15)) * 64 + kf * 32 + (lane >> 4) * 8];
#pragma unroll
    for (int kf = 0; kf < 2; ++kf)
#pragma unroll
      for (int nf = 0; nf < 4; ++nf)
        bfr[kf][nf] = *(const bf16x8*)&Bs[(wn * 64 + nf * 16 + (lane & 15)) * 64 + kf * 32 + (lane >> 4) * 8];

#pragma unroll
    for (int mf = 0; mf < 4; ++mf)
#pragma unroll
      for (int nf = 0; nf < 4; ++nf) {
        acc[mf][nf] = __builtin_amdgcn_mfma_f32_16x16x32_bf16(af[0][mf], bfr[0][nf], acc[mf][nf], 0, 0, 0);
        acc[mf][nf] = __builtin_amdgcn_mfma_f32_16x16x32_bf16(af[1][mf], bfr[1][nf], acc[mf][nf], 0, 0, 0);
      }
    __syncthreads();
  }

  u16* dst = (n0 < 768 ? ps : ts) + (size_t)b * MPAD * DD;
  const float* cv = (n0 < 768 ? cp : ct) + b * DD;
  const int ncol0 = n0 - (n0 < 768 ? 0 : 768);
#pragma unroll
  for (int mf = 0; mf < 4; ++mf)
#pragma unroll
    for (int nf = 0; nf < 4; ++nf)
#pragma unroll
      for (int r = 0; r < 4; ++r) {
        int row = m0 + wm * 64 + mf * 16 + (lane >> 4) * 4 + r;
        int col = ncol0 + wn * 64 + nf * 16 + (lane & 15);
        dst[(size_t)row * DD + col] = f2bf(acc[mf][nf][r] + cv[col]);
      }
}

// ---------------- table max ----------------
__global__ void table_max_kernel(const u16* __restrict__ ts, const int* __restrict__ ids,
                                 u16* __restrict__ tmax) {
  int bi = blockIdx.x;  // 4*60*3 = 720
  int b = bi / 180;
  int rem = bi % 180;
  int tok = rem / 3;
  int dc = rem % 3;
  int d = dc * 256 + threadIdx.x;
  __shared__ int sids[100];
  if (threadIdx.x < 100) sids[threadIdx.x] = ids[b * 100 + threadIdx.x];
  __syncthreads();
  float m[NUM_TABLES];
#pragma unroll
  for (int t = 0; t < NUM_TABLES; ++t) m[t] = -INFINITY;
  const u16* base = ts + ((size_t)b * MPAD + tok) * DD + d;
  for (int p = 0; p < 100; ++p) {
    float v = bf2f(base[(size_t)p * 60 * DD]);
    int id = sids[p];
#pragma unroll
    for (int t = 0; t < NUM_TABLES; ++t)
      if (id == t) m[t] = fmaxf(m[t], v);
  }
#pragma unroll
  for (int t = 0; t < NUM_TABLES; ++t)
    tmax[(((size_t)b * NUM_TABLES + t) * 60 + tok) * DD + d] = f2bf(m[t]);
}

// ---------------- gemm3 + fused score ----------------
// H(row,col) = sum_k [ps | tmax-gather](row,k) * Wf1b(col,k); epilogue:
// s(row) = sum_col relu(H+bf1[col])*w2[col]; LDS per-passage reduce, then
// atomicAdd(out[b,p], sum_row mask*s).
__global__ __launch_bounds__(256, 2)
void gemm3s(const u16* __restrict__ ps, const u16* __restrict__ tmax,
            const int* __restrict__ ids, const u16* __restrict__ Wf1b,
            const float* __restrict__ bf1, const float* __restrict__ w2,
            const float* __restrict__ mask, float* __restrict__ out) {
  int flat = blockIdx.x;
  int lid = (flat & 7) * 141 + (flat >> 3);
  int n = lid % 6;
  int m = (lid / 6) % 47;
  int b = lid / 282;

  const int m0 = m * 128;
  const int n0 = n * 128;
  const int tid = threadIdx.x;
  const int lane = tid & 63;
  const int wid = tid >> 6;
  const int wm = wid >> 1, wn = wid & 1;

  __shared__ u16 As[128 * 64];
  __shared__ u16 Bs[128 * 64];
  __shared__ int sids[100];
  __shared__ float pacc[4];
  if (tid < 100) sids[tid] = ids[b * 100 + tid];
  if (tid < 4) pacc[tid] = 0.f;
  __syncthreads();

  const u16* Abase = ps + (size_t)b * MPAD * DD;
  const u16* Tbase = tmax + (size_t)b * NUM_TABLES * 60 * DD;

  f32x4 acc[4][4] = {};

  const int lrow = lane >> 3;
  const int lcol = (lane & 7) * 8;

  // precompute all staging pointers (once; K-loop only increments)
  const u16* aptr[4];
  const u16* tptr[4];
  const u16* bptr[4];
#pragma unroll
  for (int j = 0; j < 4; ++j) {
    int row = m0 + wid * 32 + j * 8 + lrow;
    aptr[j] = Abase + (size_t)row * DD + lcol;
    int rp = row < 6000 ? row : 5999;
    int p = (unsigned)rp / 60u;
    int tok = rp - p * 60;
    int id = sids[p];
    tptr[j] = Tbase + ((size_t)(id * 60 + tok)) * DD + lcol;
    bptr[j] = Wf1b + (size_t)(n0 + wid * 32 + j * 8 + lrow) * 1536 + lcol;
  }

  // phase A: K 0..767 from ps
  for (int kt = 0; kt < 12; ++kt) {
#pragma unroll
    for (int j = 0; j < 4; ++j) gload_lds16(aptr[j], &As[(wid * 32 + j * 8) * 64]);
#pragma unroll
    for (int j = 0; j < 4; ++j) gload_lds16(bptr[j], &Bs[(wid * 32 + j * 8) * 64]);
#pragma unroll
    for (int j = 0; j < 4; ++j) { aptr[j] += 64; bptr[j] += 64; }
    __syncthreads();

    bf16x8 af[2][4], bfr[2][4];
#pragma unroll
    for (int kf = 0; kf < 2; ++kf)
#pragma unroll
      for (int mf = 0; mf < 4; ++mf)
        af[kf][mf] = *(const bf16x8*)&As[(wm * 64 + mf * 16 + (lane & 15)) * 64 + kf * 32 + (lane >> 4) * 8];
#pragma unroll
    for (int kf = 0; kf < 2; ++kf)
#pragma unroll
      for (int nf = 0; nf < 4; ++nf)
        bfr[kf][nf] = *(const bf16x8*)&Bs[(wn * 64 + nf * 16 + (lane & 15)) * 64 + kf * 32 + (lane >> 4) * 8];

#pragma unroll
    for (int mf = 0; mf < 4; ++mf)
#pragma unroll
      for (int nf = 0; nf < 4; ++nf) {
        acc[mf][nf] = __builtin_amdgcn_mfma_f32_16x16x32_bf16(af[0][mf], bfr[0][nf], acc[mf][nf], 0, 0, 0);
        acc[mf][nf] = __builtin_amdgcn_mfma_f32_16x16x32_bf16(af[1][mf], bfr[1][nf], acc[mf][nf], 0, 0, 0);
      }
    __syncthreads();
  }

  // phase B: K 768..1535 from tmax gather
  for (int kt = 0; kt < 12; ++kt) {
#pragma unroll
    for (int j = 0; j < 4; ++j) gload_lds16(tptr[j], &As[(wid * 32 + j * 8) * 64]);
#pragma unroll
    for (int j = 0; j < 4; ++j) gload_lds16(bptr[j], &Bs[(wid * 32 + j * 8) * 64]);
#pragma unroll
    for (int j = 0; j < 4; ++j) { tptr[j] += 64; bptr[j] += 64; }
    __syncthreads();

    bf16x8 af[2][4], bfr[2][4];
#pragma unroll
    for (int kf = 0; kf < 2; ++kf)
#pragma unroll
      for (int mf = 0; mf < 4; ++mf)
        af[kf][mf] = *(const bf16x8*)&As[(wm * 64 + mf * 16 + (lane & 15)) * 64 + kf * 32 + (lane >> 4) * 8];
#pragma unroll
    for (int kf = 0; kf < 2; ++kf)
#pragma unroll
      for (int nf = 0; nf < 4; ++nf)
        bfr[kf][nf] = *(const bf16x8*)&Bs[(wn * 64 + nf * 16 + (lane & 15)) * 64 + kf * 32 + (lane >> 4) * 8];

#pragma unroll
    for (int mf = 0; mf < 4; ++mf)
#pragma unroll
      for (int nf = 0; nf < 4; ++nf) {
        acc[mf][nf] = __builtin_amdgcn_mfma_f32_16x16x32_bf16(af[0][mf], bfr[0][nf], acc[mf][nf], 0, 0, 0);
        acc[mf][nf] = __builtin_amdgcn_mfma_f32_16x16x32_bf16(af[1][mf], bfr[1][nf], acc[mf][nf], 0, 0, 0);
      }
    __syncthreads();
  }

  // fused score epilogue: per-row col-partials -> LDS passage slots -> atomics
  float b1v[4], w2v[4];
#pragma unroll
  for (int nf = 0; nf < 4; ++nf) {
    int c = n0 + wn * 64 + nf * 16 + (lane & 15);
    b1v[nf] = bf1[c];
    w2v[nf] = w2[c];
  }
  const int pfirst = m0 / 60;
#pragma unroll
  for (int mf = 0; mf < 4; ++mf)
#pragma unroll
    for (int r = 0; r < 4; ++r) {
      int row = m0 + wm * 64 + mf * 16 + (lane >> 4) * 4 + r;
      float s = 0.f;
#pragma unroll
      for (int nf = 0; nf < 4; ++nf)
        s += fmaxf(acc[mf][nf][r] + b1v[nf], 0.f) * w2v[nf];
      s += __shfl_xor(s, 1);
      s += __shfl_xor(s, 2);
      s += __shfl_xor(s, 4);
      s += __shfl_xor(s, 8);
      if ((lane & 15) == 0 && row < 6000) {
        int p = (unsigned)row / 60u;
        int tok = row - p * 60;
        float mk = mask[((size_t)b * 100 + p) * 60 + tok];
        atomicAdd(&pacc[p - pfirst], mk * s);
      }
    }
  __syncthreads();
  int plast = (m0 + 127 < 6000 ? m0 + 127 : 5999) / 60;
  if (tid <= plast - pfirst)
    atomicAdd(out + b * 100 + pfirst + tid, pacc[tid]);
}

// ---------------- launch ----------------
extern "C" void kernel_launch(void* const* d_in, const int* in_sizes, int n_in,
                              void* d_out, int out_size, void* d_ws, size_t ws_size,
                              hipStream_t stream) {
  const float* answer = (const float*)d_in[0];
  const float* qps    = (const float*)d_in[1];
  const float* mask   = (const float*)d_in[2];
  const int*   tids   = (const int*)d_in[3];
  const float* Wp     = (const float*)d_in[4];
  const float* bp     = (const float*)d_in[5];
  const float* Wt     = (const float*)d_in[6];
  const float* bt     = (const float*)d_in[7];
  const float* Wf1    = (const float*)d_in[8];
  const float* bf1    = (const float*)d_in[9];
  const float* Wf2    = (const float*)d_in[10];
  const float* bf2    = (const float*)d_in[11];
  float* out = (float*)d_out;

  char* ws = (char*)d_ws;
  u16* Qpad = (u16*)(ws + 0);            // 36,962,304
  u16* ps   = (u16*)(ws + 36962304);     // 36,962,304
  u16* ts   = (u16*)(ws + 73924608);     // 36,962,304
  u16* Bcat = (u16*)(ws + 110886912);    // 9,437,184
  u16* Wf1b = (u16*)(ws + 120324096);    // 2,359,296
  float* cp = (float*)(ws + 122683392);  // 12,288
  float* ct = (float*)(ws + 122695680);  // 12,288
  u16* tmax = (u16*)(ws + 122707968);    // 3,686,400

  init_out<<<2, 256, 0, stream>>>(mask, bf2, out);
  prep_q<<<9024, 256, 0, stream>>>(qps, (uint4*)Qpad);
  prep_wcomb<<<2304, 256, 0, stream>>>(answer, Wp, Wt, Bcat);
  prep_consts<<<12, 256, 0, stream>>>(answer, Wp, bp, Wt, bt, cp, ct);
  prep_wf1<<<576, 256, 0, stream>>>(Wf1, (uint4*)Wf1b);

  gemm12<<<2256, 256, 0, stream>>>(Qpad, Bcat, cp, ct, ps, ts);

  table_max_kernel<<<720, 256, 0, stream>>>(ts, tids, tmax);

  gemm3s<<<1128, 256, 0, stream>>>(ps, tmax, tids, Wf1b, bf1, Wf2, mask, out);
}

// Round 4
// 299.445 us; speedup vs baseline: 2.2491x; 1.0299x over previous
//
#include <hip/hip_runtime.h>
#include <hip/hip_bf16.h>

// FusionRetrModel: B=4, NL=2 (only l=1 used), P=100, TOK=60, T=6000, D=768.
// R4 pipeline:
//   prep_all (one dispatch): Qpad bf16 [4][6016][768]; Bcat[b]=[Wpb;Wtb];
//         cp/ct; Wf1 bf16; out init = bf2*msum.
//   gemm12: [ps|ts] = Qpad @ Bcat^T + [cp|ct]   (dbuf 2-phase, swizzled LDS)
//   tmax:   per-table elementwise max over passages (from ts)
//   gemm3s: H = [ps | tmax-indirect] @ Wf1^T, fused relu/w2/mask/score epilogue
// GEMM structure: 128x128 tile, BK=64, 4 waves 2x2; double-buffered LDS with
// STAGE(t+1) issued before compute(t), ONE barrier per K-step; T2 XOR swizzle
// via pre-swizzled global source (LDS linear) + swizzled ds_read (rule 21).
// Workspace: 126,394,368 bytes.

typedef unsigned short u16;
typedef unsigned int u32;
typedef __attribute__((ext_vector_type(8))) short bf16x8;
typedef __attribute__((ext_vector_type(4))) float f32x4;

#define NUM_TABLES 10
#define MPAD 6016
#define DD 768

__device__ __forceinline__ u16 f2bf(float f) {
  u32 u = __builtin_bit_cast(u32, f);
  u32 r = u + 0x7FFFu + ((u >> 16) & 1u);
  return (u16)(r >> 16);
}
__device__ __forceinline__ float bf2f(u16 h) {
  u32 u = ((u32)h) << 16;
  return __builtin_bit_cast(float, u);
}

__device__ __forceinline__ void gload_lds16(const u16* g, u16* l) {
  __builtin_amdgcn_global_load_lds(
      (const __attribute__((address_space(1))) void*)g,
      (__attribute__((address_space(3))) void*)l, 16, 0, 0);
}

// ---------------- fused prep (one dispatch) ----------------
__global__ void prep_all(const float* __restrict__ qps, uint4* __restrict__ qpad,
                         const float* __restrict__ Ans, const float* __restrict__ Wp,
                         const float* __restrict__ Wt, u16* __restrict__ Bcat,
                         const float* __restrict__ Wf1, uint4* __restrict__ Wf1b,
                         const float* __restrict__ bp, const float* __restrict__ bt,
                         float* __restrict__ cp, float* __restrict__ ct,
                         const float* __restrict__ mask, const float* __restrict__ bf2,
                         float* __restrict__ out) {
  int blk = blockIdx.x;
  int tid = threadIdx.x;
  if (blk < 9024) {
    // ---- Qpad: cast l=1 slice to bf16, pad rows [6000,6016) ----
    size_t c = (size_t)blk * 256 + tid;
    const int per_b = MPAD * (DD / 8);
    if (c >= (size_t)4 * per_b) return;
    int b = (int)(c / per_b);
    int rr = (int)(c % per_b);
    int r = rr / (DD / 8);
    int kc = rr % (DD / 8);
    uint4 o;
    if (r < 6000) {
      const float* src = qps + (((size_t)(b * 2 + 1)) * 6000 + r) * DD + kc * 8;
      float4 f0 = *(const float4*)src;
      float4 f1 = *(const float4*)(src + 4);
      o.x = (u32)f2bf(f0.x) | ((u32)f2bf(f0.y) << 16);
      o.y = (u32)f2bf(f0.z) | ((u32)f2bf(f0.w) << 16);
      o.z = (u32)f2bf(f1.x) | ((u32)f2bf(f1.y) << 16);
      o.w = (u32)f2bf(f1.z) | ((u32)f2bf(f1.w) << 16);
    } else {
      o = make_uint4(0, 0, 0, 0);
    }
    qpad[c] = o;
  } else if (blk < 11328) {
    // ---- Bcat = [Wp2 + A*Wp3 ; Wt2 + A*Wt3] ----
    size_t c = (size_t)(blk - 9024) * 256 + tid;
    const int per_b = DD * (DD / 4);
    if (c >= (size_t)4 * per_b) return;
    int b = (int)(c / per_b);
    int rr = (int)(c % per_b);
    int d = rr / (DD / 4);
    int k4 = (rr % (DD / 4)) * 4;
    float4 av = *(const float4*)(Ans + ((size_t)b * 2 + 1) * DD + k4);
    float4 p2 = *(const float4*)(Wp + (size_t)d * 2304 + 768 + k4);
    float4 p3 = *(const float4*)(Wp + (size_t)d * 2304 + 1536 + k4);
    float4 t2 = *(const float4*)(Wt + (size_t)d * 2304 + 768 + k4);
    float4 t3 = *(const float4*)(Wt + (size_t)d * 2304 + 1536 + k4);
    uint2 op, ot;
    op.x = (u32)f2bf(p2.x + av.x * p3.x) | ((u32)f2bf(p2.y + av.y * p3.y) << 16);
    op.y = (u32)f2bf(p2.z + av.z * p3.z) | ((u32)f2bf(p2.w + av.w * p3.w) << 16);
    ot.x = (u32)f2bf(t2.x + av.x * t3.x) | ((u32)f2bf(t2.y + av.y * t3.y) << 16);
    ot.y = (u32)f2bf(t2.z + av.z * t3.z) | ((u32)f2bf(t2.w + av.w * t3.w) << 16);
    size_t ip = ((size_t)b * 1536 + d) * DD + k4;
    size_t it = ((size_t)b * 1536 + 768 + d) * DD + k4;
    *(uint2*)(Bcat + ip) = op;
    *(uint2*)(Bcat + it) = ot;
  } else if (blk < 11904) {
    // ---- Wf1 cast ----
    size_t c = (size_t)(blk - 11328) * 256 + tid;
    if (c >= (size_t)DD * 1536 / 8) return;
    const float* src = Wf1 + c * 8;
    float4 f0 = *(const float4*)src;
    float4 f1 = *(const float4*)(src + 4);
    uint4 o;
    o.x = (u32)f2bf(f0.x) | ((u32)f2bf(f0.y) << 16);
    o.y = (u32)f2bf(f0.z) | ((u32)f2bf(f0.w) << 16);
    o.z = (u32)f2bf(f1.x) | ((u32)f2bf(f1.y) << 16);
    o.w = (u32)f2bf(f1.z) | ((u32)f2bf(f1.w) << 16);
    Wf1b[c] = o;
  } else if (blk < 11916) {
    // ---- cp/ct ----
    int idx = (blk - 11904) * 256 + tid;
    if (idx >= 4 * DD) return;
    int b = idx / DD, d = idx % DD;
    const float* a = Ans + ((size_t)b * 2 + 1) * DD;
    const float* wp = Wp + (size_t)d * 2304;
    const float* wt = Wt + (size_t)d * 2304;
    float sp = 0.f, st = 0.f;
    for (int k = 0; k < DD; k += 4) {
      float4 av = *(const float4*)(a + k);
      float4 pv = *(const float4*)(wp + k);
      float4 tv = *(const float4*)(wt + k);
      sp += av.x * pv.x + av.y * pv.y + av.z * pv.z + av.w * pv.w;
      st += av.x * tv.x + av.y * tv.y + av.z * tv.z + av.w * tv.w;
    }
    cp[idx] = sp + bp[d];
    ct[idx] = st + bt[d];
  } else {
    // ---- out init = bf2 * msum ----
    int idx = (blk - 11916) * 256 + tid;
    if (idx >= 400) return;
    const float* m = mask + (size_t)idx * 60;
    float s = 0.f;
    for (int t = 0; t < 60; ++t) s += m[t];
    out[idx] = bf2[0] * s;
  }
}

// ---------------- gemm12: [ps|ts] = Qpad @ Bcat^T + [cp|ct] ----------------
// dbuf 2-phase + swizzle. Grid 2256 flat, XCD-chunked, n-fastest.
__global__ __launch_bounds__(256, 2)
void gemm12(const u16* __restrict__ Q, const u16* __restrict__ Bcat,
            const float* __restrict__ cp, const float* __restrict__ ct,
            u16* __restrict__ ps, u16* __restrict__ ts) {
  int flat = blockIdx.x;
  int lid = (flat & 7) * 282 + (flat >> 3);
  int n = lid % 12;
  int m = (lid / 12) % 47;
  int b = lid / 564;

  const int m0 = m * 128;
  const int n0 = n * 128;
  const int tid = threadIdx.x;
  const int lane = tid & 63;
  const int wid = tid >> 6;
  const int wm = wid >> 1, wn = wid & 1;

  __shared__ u16 As[2][128 * 64];
  __shared__ u16 Bs[2][128 * 64];

  const u16* Abase = Q + (size_t)b * MPAD * DD;
  const u16* Bbase = Bcat + (size_t)b * 1536 * DD;

  f32x4 acc[4][4] = {};

  const int lrow = lane >> 3;
  // pre-swizzled global column (LDS stays linear; rule 21)
  const int lcol_s = (((lane & 7) ^ (lrow & 7)) * 8);
  const int axor = (lane & 7) << 3;  // read-side XOR (row_e&7)<<3 with row_e&7==lane&7

  const u16* aptr[4];
  const u16* bptr[4];
#pragma unroll
  for (int j = 0; j < 4; ++j) {
    aptr[j] = Abase + (size_t)(m0 + wid * 32 + j * 8 + lrow) * DD + lcol_s;
    bptr[j] = Bbase + (size_t)(n0 + wid * 32 + j * 8 + lrow) * DD + lcol_s;
  }

  // prologue: stage kt=0 into buf 0
#pragma unroll
  for (int j = 0; j < 4; ++j) {
    gload_lds16(aptr[j], &As[0][(wid * 32 + j * 8) * 64]);
    gload_lds16(bptr[j], &Bs[0][(wid * 32 + j * 8) * 64]);
    aptr[j] += 64; bptr[j] += 64;
  }
  __syncthreads();

  int cur = 0;
  for (int kt = 0; kt < 12; ++kt) {
    if (kt < 11) {
#pragma unroll
      for (int j = 0; j < 4; ++j) {
        gload_lds16(aptr[j], &As[cur ^ 1][(wid * 32 + j * 8) * 64]);
        gload_lds16(bptr[j], &Bs[cur ^ 1][(wid * 32 + j * 8) * 64]);
        aptr[j] += 64; bptr[j] += 64;
      }
    }

    bf16x8 af[2][4], bfr[2][4];
#pragma unroll
    for (int kf = 0; kf < 2; ++kf)
#pragma unroll
      for (int mf = 0; mf < 4; ++mf)
        af[kf][mf] = *(const bf16x8*)&As[cur][(wm * 64 + mf * 16 + (lane & 15)) * 64 + ((kf * 32 + (lane >> 4) * 8) ^ axor)];
#pragma unroll
    for (int kf = 0; kf < 2; ++kf)
#pragma unroll
      for (int nf = 0; nf < 4; ++nf)
        bfr[kf][nf] = *(const bf16x8*)&Bs[cur][(wn * 64 + nf * 16 + (lane & 15)) * 64 + ((kf * 32 + (lane >> 4) * 8) ^ axor)];

#pragma unroll
    for (int mf = 0; mf < 4; ++mf)
#pragma unroll
      for (int nf = 0; nf < 4; ++nf) {
        acc[mf][nf] = __builtin_amdgcn_mfma_f32_16x16x32_bf16(af[0][mf], bfr[0][nf], acc[mf][nf], 0, 0, 0);
        acc[mf][nf] = __builtin_amdgcn_mfma_f32_16x16x32_bf16(af[1][mf], bfr[1][nf], acc[mf][nf], 0, 0, 0);
      }
    __syncthreads();
    cur ^= 1;
  }

  u16* dst = (n0 < 768 ? ps : ts) + (size_t)b * MPAD * DD;
  const float* cv = (n0 < 768 ? cp : ct) + b * DD;
  const int ncol0 = n0 - (n0 < 768 ? 0 : 768);
#pragma unroll
  for (int mf = 0; mf < 4; ++mf)
#pragma unroll
    for (int nf = 0; nf < 4; ++nf)
#pragma unroll
      for (int r = 0; r < 4; ++r) {
        int row = m0 + wm * 64 + mf * 16 + (lane >> 4) * 4 + r;
        int col = ncol0 + wn * 64 + nf * 16 + (lane & 15);
        dst[(size_t)row * DD + col] = f2bf(acc[mf][nf][r] + cv[col]);
      }
}

// ---------------- table max ----------------
__global__ void table_max_kernel(const u16* __restrict__ ts, const int* __restrict__ ids,
                                 u16* __restrict__ tmax) {
  int bi = blockIdx.x;  // 4*60*3 = 720
  int b = bi / 180;
  int rem = bi % 180;
  int tok = rem / 3;
  int dc = rem % 3;
  int d = dc * 256 + threadIdx.x;
  __shared__ int sids[100];
  if (threadIdx.x < 100) sids[threadIdx.x] = ids[b * 100 + threadIdx.x];
  __syncthreads();
  float m[NUM_TABLES];
#pragma unroll
  for (int t = 0; t < NUM_TABLES; ++t) m[t] = -INFINITY;
  const u16* base = ts + ((size_t)b * MPAD + tok) * DD + d;
  for (int p = 0; p < 100; ++p) {
    float v = bf2f(base[(size_t)p * 60 * DD]);
    int id = sids[p];
#pragma unroll
    for (int t = 0; t < NUM_TABLES; ++t)
      if (id == t) m[t] = fmaxf(m[t], v);
  }
#pragma unroll
  for (int t = 0; t < NUM_TABLES; ++t)
    tmax[(((size_t)b * NUM_TABLES + t) * 60 + tok) * DD + d] = f2bf(m[t]);
}

// ---------------- gemm3 + fused score ----------------
__global__ __launch_bounds__(256, 2)
void gemm3s(const u16* __restrict__ ps, const u16* __restrict__ tmax,
            const int* __restrict__ ids, const u16* __restrict__ Wf1b,
            const float* __restrict__ bf1, const float* __restrict__ w2,
            const float* __restrict__ mask, float* __restrict__ out) {
  int flat = blockIdx.x;
  int lid = (flat & 7) * 141 + (flat >> 3);
  int n = lid % 6;
  int m = (lid / 6) % 47;
  int b = lid / 282;

  const int m0 = m * 128;
  const int n0 = n * 128;
  const int tid = threadIdx.x;
  const int lane = tid & 63;
  const int wid = tid >> 6;
  const int wm = wid >> 1, wn = wid & 1;

  __shared__ u16 As[2][128 * 64];
  __shared__ u16 Bs[2][128 * 64];
  __shared__ int sids[100];
  __shared__ float pacc[4];
  if (tid < 100) sids[tid] = ids[b * 100 + tid];
  if (tid < 4) pacc[tid] = 0.f;
  __syncthreads();

  const u16* Abase = ps + (size_t)b * MPAD * DD;
  const u16* Tbase = tmax + (size_t)b * NUM_TABLES * 60 * DD;

  f32x4 acc[4][4] = {};

  const int lrow = lane >> 3;
  const int lcol_s = (((lane & 7) ^ (lrow & 7)) * 8);
  const int axor = (lane & 7) << 3;

  const u16* aptr[4];
  const u16* tptr[4];
  const u16* bptr[4];
#pragma unroll
  for (int j = 0; j < 4; ++j) {
    int row = m0 + wid * 32 + j * 8 + lrow;
    aptr[j] = Abase + (size_t)row * DD + lcol_s;
    int rp = row < 6000 ? row : 5999;
    int p = (unsigned)rp / 60u;
    int tok = rp - p * 60;
    int id = sids[p];
    tptr[j] = Tbase + ((size_t)(id * 60 + tok)) * DD + lcol_s;
    bptr[j] = Wf1b + (size_t)(n0 + wid * 32 + j * 8 + lrow) * 1536 + lcol_s;
  }

  // prologue: stage kt=0 into buf 0 (from ps)
#pragma unroll
  for (int j = 0; j < 4; ++j) {
    gload_lds16(aptr[j], &As[0][(wid * 32 + j * 8) * 64]);
    gload_lds16(bptr[j], &Bs[0][(wid * 32 + j * 8) * 64]);
    aptr[j] += 64; bptr[j] += 64;
  }
  __syncthreads();

  int cur = 0;
  for (int kt = 0; kt < 24; ++kt) {
    if (kt < 23) {
      if (kt + 1 == 12) {
#pragma unroll
        for (int j = 0; j < 4; ++j) aptr[j] = tptr[j];  // switch A source to tmax gather
      }
#pragma unroll
      for (int j = 0; j < 4; ++j) {
        gload_lds16(aptr[j], &As[cur ^ 1][(wid * 32 + j * 8) * 64]);
        gload_lds16(bptr[j], &Bs[cur ^ 1][(wid * 32 + j * 8) * 64]);
        aptr[j] += 64; bptr[j] += 64;
      }
    }

    bf16x8 af[2][4], bfr[2][4];
#pragma unroll
    for (int kf = 0; kf < 2; ++kf)
#pragma unroll
      for (int mf = 0; mf < 4; ++mf)
        af[kf][mf] = *(const bf16x8*)&As[cur][(wm * 64 + mf * 16 + (lane & 15)) * 64 + ((kf * 32 + (lane >> 4) * 8) ^ axor)];
#pragma unroll
    for (int kf = 0; kf < 2; ++kf)
#pragma unroll
      for (int nf = 0; nf < 4; ++nf)
        bfr[kf][nf] = *(const bf16x8*)&Bs[cur][(wn * 64 + nf * 16 + (lane & 15)) * 64 + ((kf * 32 + (lane >> 4) * 8) ^ axor)];

#pragma unroll
    for (int mf = 0; mf < 4; ++mf)
#pragma unroll
      for (int nf = 0; nf < 4; ++nf) {
        acc[mf][nf] = __builtin_amdgcn_mfma_f32_16x16x32_bf16(af[0][mf], bfr[0][nf], acc[mf][nf], 0, 0, 0);
        acc[mf][nf] = __builtin_amdgcn_mfma_f32_16x16x32_bf16(af[1][mf], bfr[1][nf], acc[mf][nf], 0, 0, 0);
      }
    __syncthreads();
    cur ^= 1;
  }

  // fused score epilogue
  float b1v[4], w2v[4];
#pragma unroll
  for (int nf = 0; nf < 4; ++nf) {
    int c = n0 + wn * 64 + nf * 16 + (lane & 15);
    b1v[nf] = bf1[c];
    w2v[nf] = w2[c];
  }
  const int pfirst = m0 / 60;
#pragma unroll
  for (int mf = 0; mf < 4; ++mf)
#pragma unroll
    for (int r = 0; r < 4; ++r) {
      int row = m0 + wm * 64 + mf * 16 + (lane >> 4) * 4 + r;
      float s = 0.f;
#pragma unroll
      for (int nf = 0; nf < 4; ++nf)
        s += fmaxf(acc[mf][nf][r] + b1v[nf], 0.f) * w2v[nf];
      s += __shfl_xor(s, 1);
      s += __shfl_xor(s, 2);
      s += __shfl_xor(s, 4);
      s += __shfl_xor(s, 8);
      if ((lane & 15) == 0 && row < 6000) {
        int p = (unsigned)row / 60u;
        int tok = row - p * 60;
        float mk = mask[((size_t)b * 100 + p) * 60 + tok];
        atomicAdd(&pacc[p - pfirst], mk * s);
      }
    }
  __syncthreads();
  int plast = (m0 + 127 < 6000 ? m0 + 127 : 5999) / 60;
  if (tid <= plast - pfirst)
    atomicAdd(out + b * 100 + pfirst + tid, pacc[tid]);
}

// ---------------- launch ----------------
extern "C" void kernel_launch(void* const* d_in, const int* in_sizes, int n_in,
                              void* d_out, int out_size, void* d_ws, size_t ws_size,
                              hipStream_t stream) {
  const float* answer = (const float*)d_in[0];
  const float* qps    = (const float*)d_in[1];
  const float* mask   = (const float*)d_in[2];
  const int*   tids   = (const int*)d_in[3];
  const float* Wp     = (const float*)d_in[4];
  const float* bp     = (const float*)d_in[5];
  const float* Wt     = (const float*)d_in[6];
  const float* bt     = (const float*)d_in[7];
  const float* Wf1    = (const float*)d_in[8];
  const float* bf1    = (const float*)d_in[9];
  const float* Wf2    = (const float*)d_in[10];
  const float* bf2    = (const float*)d_in[11];
  float* out = (float*)d_out;

  char* ws = (char*)d_ws;
  u16* Qpad = (u16*)(ws + 0);            // 36,962,304
  u16* ps   = (u16*)(ws + 36962304);     // 36,962,304
  u16* ts   = (u16*)(ws + 73924608);     // 36,962,304
  u16* Bcat = (u16*)(ws + 110886912);    // 9,437,184
  u16* Wf1b = (u16*)(ws + 120324096);    // 2,359,296
  float* cp = (float*)(ws + 122683392);  // 12,288
  float* ct = (float*)(ws + 122695680);  // 12,288
  u16* tmax = (u16*)(ws + 122707968);    // 3,686,400

  prep_all<<<11918, 256, 0, stream>>>(qps, (uint4*)Qpad, answer, Wp, Wt, Bcat,
                                      Wf1, (uint4*)Wf1b, bp, bt, cp, ct,
                                      mask, bf2, out);

  gemm12<<<2256, 256, 0, stream>>>(Qpad, Bcat, cp, ct, ps, ts);

  table_max_kernel<<<720, 256, 0, stream>>>(ts, tids, tmax);

  gemm3s<<<1128, 256, 0, stream>>>(ps, tmax, tids, Wf1b, bf1, Wf2, mask, out);
}

// Round 5
// 232.426 us; speedup vs baseline: 2.8976x; 1.2883x over previous
//
#include <hip/hip_runtime.h>
#include <hip/hip_bf16.h>

// FusionRetrModel: B=4, NL=2 (only l=1 used), P=100, TOK=60, T=6000, D=768.
// R5 pipeline:
//   prep_all (one dispatch, all branches wide):
//     [0,9024)      Qpad bf16 [4][6016][768]
//     [9024,11328)  Bcat[b]=[Wpb;Wtb] bf16
//     [11328,11904) Wf1 cast bf16
//     [11904,13440) cp/ct parallel GEMV (1 block per (matrix,d), 256-thread reduce)
//     [13440,13442) out init = bf2*msum
//   gemm12: [ps|ts] = Qpad @ Bcat^T + [cp|ct]   (dbuf 2-phase, swizzled LDS)
//   tmax:   per-table elementwise max over passages (from ts)
//   gemm3s: H = [ps | tmax-indirect] @ Wf1^T, fused relu/w2/mask/score epilogue
// GEMM structure: 128x128 tile, BK=64, 4 waves 2x2; double-buffered LDS with
// STAGE(t+1) issued before compute(t), ONE barrier per K-step; T2 XOR swizzle
// via pre-swizzled global source (LDS linear) + swizzled ds_read (rule 21).
// Workspace: 126,394,368 bytes.

typedef unsigned short u16;
typedef unsigned int u32;
typedef __attribute__((ext_vector_type(8))) short bf16x8;
typedef __attribute__((ext_vector_type(4))) float f32x4;

#define NUM_TABLES 10
#define MPAD 6016
#define DD 768

__device__ __forceinline__ u16 f2bf(float f) {
  u32 u = __builtin_bit_cast(u32, f);
  u32 r = u + 0x7FFFu + ((u >> 16) & 1u);
  return (u16)(r >> 16);
}
__device__ __forceinline__ float bf2f(u16 h) {
  u32 u = ((u32)h) << 16;
  return __builtin_bit_cast(float, u);
}

__device__ __forceinline__ void gload_lds16(const u16* g, u16* l) {
  __builtin_amdgcn_global_load_lds(
      (const __attribute__((address_space(1))) void*)g,
      (__attribute__((address_space(3))) void*)l, 16, 0, 0);
}

// ---------------- fused prep (one dispatch) ----------------
__global__ void prep_all(const float* __restrict__ qps, uint4* __restrict__ qpad,
                         const float* __restrict__ Ans, const float* __restrict__ Wp,
                         const float* __restrict__ Wt, u16* __restrict__ Bcat,
                         const float* __restrict__ Wf1, uint4* __restrict__ Wf1b,
                         const float* __restrict__ bp, const float* __restrict__ bt,
                         float* __restrict__ cp, float* __restrict__ ct,
                         const float* __restrict__ mask, const float* __restrict__ bf2,
                         float* __restrict__ out) {
  int blk = blockIdx.x;
  int tid = threadIdx.x;
  if (blk < 9024) {
    // ---- Qpad: cast l=1 slice to bf16, pad rows [6000,6016) ----
    size_t c = (size_t)blk * 256 + tid;
    const int per_b = MPAD * (DD / 8);
    if (c >= (size_t)4 * per_b) return;
    int b = (int)(c / per_b);
    int rr = (int)(c % per_b);
    int r = rr / (DD / 8);
    int kc = rr % (DD / 8);
    uint4 o;
    if (r < 6000) {
      const float* src = qps + (((size_t)(b * 2 + 1)) * 6000 + r) * DD + kc * 8;
      float4 f0 = *(const float4*)src;
      float4 f1 = *(const float4*)(src + 4);
      o.x = (u32)f2bf(f0.x) | ((u32)f2bf(f0.y) << 16);
      o.y = (u32)f2bf(f0.z) | ((u32)f2bf(f0.w) << 16);
      o.z = (u32)f2bf(f1.x) | ((u32)f2bf(f1.y) << 16);
      o.w = (u32)f2bf(f1.z) | ((u32)f2bf(f1.w) << 16);
    } else {
      o = make_uint4(0, 0, 0, 0);
    }
    qpad[c] = o;
  } else if (blk < 11328) {
    // ---- Bcat = [Wp2 + A*Wp3 ; Wt2 + A*Wt3] ----
    size_t c = (size_t)(blk - 9024) * 256 + tid;
    const int per_b = DD * (DD / 4);
    if (c >= (size_t)4 * per_b) return;
    int b = (int)(c / per_b);
    int rr = (int)(c % per_b);
    int d = rr / (DD / 4);
    int k4 = (rr % (DD / 4)) * 4;
    float4 av = *(const float4*)(Ans + ((size_t)b * 2 + 1) * DD + k4);
    float4 p2 = *(const float4*)(Wp + (size_t)d * 2304 + 768 + k4);
    float4 p3 = *(const float4*)(Wp + (size_t)d * 2304 + 1536 + k4);
    float4 t2 = *(const float4*)(Wt + (size_t)d * 2304 + 768 + k4);
    float4 t3 = *(const float4*)(Wt + (size_t)d * 2304 + 1536 + k4);
    uint2 op, ot;
    op.x = (u32)f2bf(p2.x + av.x * p3.x) | ((u32)f2bf(p2.y + av.y * p3.y) << 16);
    op.y = (u32)f2bf(p2.z + av.z * p3.z) | ((u32)f2bf(p2.w + av.w * p3.w) << 16);
    ot.x = (u32)f2bf(t2.x + av.x * t3.x) | ((u32)f2bf(t2.y + av.y * t3.y) << 16);
    ot.y = (u32)f2bf(t2.z + av.z * t3.z) | ((u32)f2bf(t2.w + av.w * t3.w) << 16);
    size_t ip = ((size_t)b * 1536 + d) * DD + k4;
    size_t it = ((size_t)b * 1536 + 768 + d) * DD + k4;
    *(uint2*)(Bcat + ip) = op;
    *(uint2*)(Bcat + it) = ot;
  } else if (blk < 11904) {
    // ---- Wf1 cast ----
    size_t c = (size_t)(blk - 11328) * 256 + tid;
    if (c >= (size_t)DD * 1536 / 8) return;
    const float* src = Wf1 + c * 8;
    float4 f0 = *(const float4*)src;
    float4 f1 = *(const float4*)(src + 4);
    uint4 o;
    o.x = (u32)f2bf(f0.x) | ((u32)f2bf(f0.y) << 16);
    o.y = (u32)f2bf(f0.z) | ((u32)f2bf(f0.w) << 16);
    o.z = (u32)f2bf(f1.x) | ((u32)f2bf(f1.y) << 16);
    o.w = (u32)f2bf(f1.z) | ((u32)f2bf(f1.w) << 16);
    Wf1b[c] = o;
  } else if (blk < 13440) {
    // ---- cp/ct parallel: one block per (matrix, d) ----
    int e = blk - 11904;          // 0..1535
    int isT = e >= 768;
    int d = e - (isT ? 768 : 0);
    const float* wrow = (isT ? Wt : Wp) + (size_t)d * 2304;
    float a0 = 0.f, a1 = 0.f, a2 = 0.f, a3 = 0.f;
    for (int k = tid; k < DD; k += 256) {
      float w = wrow[k];
      a0 += w * Ans[1 * DD + k];
      a1 += w * Ans[3 * DD + k];
      a2 += w * Ans[5 * DD + k];
      a3 += w * Ans[7 * DD + k];
    }
#pragma unroll
    for (int off = 32; off > 0; off >>= 1) {
      a0 += __shfl_down(a0, off);
      a1 += __shfl_down(a1, off);
      a2 += __shfl_down(a2, off);
      a3 += __shfl_down(a3, off);
    }
    __shared__ float red[4][4];
    int wid = tid >> 6;
    if ((tid & 63) == 0) {
      red[wid][0] = a0; red[wid][1] = a1; red[wid][2] = a2; red[wid][3] = a3;
    }
    __syncthreads();
    if (tid < 4) {
      float s = red[0][tid] + red[1][tid] + red[2][tid] + red[3][tid];
      float bias = (isT ? bt : bp)[d];
      (isT ? ct : cp)[tid * DD + d] = s + bias;
    }
  } else {
    // ---- out init = bf2 * msum ----
    int idx = (blk - 13440) * 256 + tid;
    if (idx >= 400) return;
    const float* m = mask + (size_t)idx * 60;
    float s = 0.f;
    for (int t = 0; t < 60; ++t) s += m[t];
    out[idx] = bf2[0] * s;
  }
}

// ---------------- gemm12: [ps|ts] = Qpad @ Bcat^T + [cp|ct] ----------------
// dbuf 2-phase + swizzle. Grid 2256 flat, XCD-chunked, n-fastest.
__global__ __launch_bounds__(256, 2)
void gemm12(const u16* __restrict__ Q, const u16* __restrict__ Bcat,
            const float* __restrict__ cp, const float* __restrict__ ct,
            u16* __restrict__ ps, u16* __restrict__ ts) {
  int flat = blockIdx.x;
  int lid = (flat & 7) * 282 + (flat >> 3);
  int n = lid % 12;
  int m = (lid / 12) % 47;
  int b = lid / 564;

  const int m0 = m * 128;
  const int n0 = n * 128;
  const int tid = threadIdx.x;
  const int lane = tid & 63;
  const int wid = tid >> 6;
  const int wm = wid >> 1, wn = wid & 1;

  __shared__ u16 As[2][128 * 64];
  __shared__ u16 Bs[2][128 * 64];

  const u16* Abase = Q + (size_t)b * MPAD * DD;
  const u16* Bbase = Bcat + (size_t)b * 1536 * DD;

  f32x4 acc[4][4] = {};

  const int lrow = lane >> 3;
  // pre-swizzled global column (LDS stays linear; rule 21)
  const int lcol_s = (((lane & 7) ^ (lrow & 7)) * 8);
  const int axor = (lane & 7) << 3;  // read-side XOR

  const u16* aptr[4];
  const u16* bptr[4];
#pragma unroll
  for (int j = 0; j < 4; ++j) {
    aptr[j] = Abase + (size_t)(m0 + wid * 32 + j * 8 + lrow) * DD + lcol_s;
    bptr[j] = Bbase + (size_t)(n0 + wid * 32 + j * 8 + lrow) * DD + lcol_s;
  }

  // prologue: stage kt=0 into buf 0
#pragma unroll
  for (int j = 0; j < 4; ++j) {
    gload_lds16(aptr[j], &As[0][(wid * 32 + j * 8) * 64]);
    gload_lds16(bptr[j], &Bs[0][(wid * 32 + j * 8) * 64]);
    aptr[j] += 64; bptr[j] += 64;
  }
  __syncthreads();

  int cur = 0;
  for (int kt = 0; kt < 12; ++kt) {
    if (kt < 11) {
#pragma unroll
      for (int j = 0; j < 4; ++j) {
        gload_lds16(aptr[j], &As[cur ^ 1][(wid * 32 + j * 8) * 64]);
        gload_lds16(bptr[j], &Bs[cur ^ 1][(wid * 32 + j * 8) * 64]);
        aptr[j] += 64; bptr[j] += 64;
      }
    }

    bf16x8 af[2][4], bfr[2][4];
#pragma unroll
    for (int kf = 0; kf < 2; ++kf)
#pragma unroll
      for (int mf = 0; mf < 4; ++mf)
        af[kf][mf] = *(const bf16x8*)&As[cur][(wm * 64 + mf * 16 + (lane & 15)) * 64 + ((kf * 32 + (lane >> 4) * 8) ^ axor)];
#pragma unroll
    for (int kf = 0; kf < 2; ++kf)
#pragma unroll
      for (int nf = 0; nf < 4; ++nf)
        bfr[kf][nf] = *(const bf16x8*)&Bs[cur][(wn * 64 + nf * 16 + (lane & 15)) * 64 + ((kf * 32 + (lane >> 4) * 8) ^ axor)];

#pragma unroll
    for (int mf = 0; mf < 4; ++mf)
#pragma unroll
      for (int nf = 0; nf < 4; ++nf) {
        acc[mf][nf] = __builtin_amdgcn_mfma_f32_16x16x32_bf16(af[0][mf], bfr[0][nf], acc[mf][nf], 0, 0, 0);
        acc[mf][nf] = __builtin_amdgcn_mfma_f32_16x16x32_bf16(af[1][mf], bfr[1][nf], acc[mf][nf], 0, 0, 0);
      }
    __syncthreads();
    cur ^= 1;
  }

  u16* dst = (n0 < 768 ? ps : ts) + (size_t)b * MPAD * DD;
  const float* cv = (n0 < 768 ? cp : ct) + b * DD;
  const int ncol0 = n0 - (n0 < 768 ? 0 : 768);
#pragma unroll
  for (int mf = 0; mf < 4; ++mf)
#pragma unroll
    for (int nf = 0; nf < 4; ++nf)
#pragma unroll
      for (int r = 0; r < 4; ++r) {
        int row = m0 + wm * 64 + mf * 16 + (lane >> 4) * 4 + r;
        int col = ncol0 + wn * 64 + nf * 16 + (lane & 15);
        dst[(size_t)row * DD + col] = f2bf(acc[mf][nf][r] + cv[col]);
      }
}

// ---------------- table max ----------------
__global__ void table_max_kernel(const u16* __restrict__ ts, const int* __restrict__ ids,
                                 u16* __restrict__ tmax) {
  int bi = blockIdx.x;  // 4*60*3 = 720
  int b = bi / 180;
  int rem = bi % 180;
  int tok = rem / 3;
  int dc = rem % 3;
  int d = dc * 256 + threadIdx.x;
  __shared__ int sids[100];
  if (threadIdx.x < 100) sids[threadIdx.x] = ids[b * 100 + threadIdx.x];
  __syncthreads();
  float m[NUM_TABLES];
#pragma unroll
  for (int t = 0; t < NUM_TABLES; ++t) m[t] = -INFINITY;
  const u16* base = ts + ((size_t)b * MPAD + tok) * DD + d;
  for (int p = 0; p < 100; ++p) {
    float v = bf2f(base[(size_t)p * 60 * DD]);
    int id = sids[p];
#pragma unroll
    for (int t = 0; t < NUM_TABLES; ++t)
      if (id == t) m[t] = fmaxf(m[t], v);
  }
#pragma unroll
  for (int t = 0; t < NUM_TABLES; ++t)
    tmax[(((size_t)b * NUM_TABLES + t) * 60 + tok) * DD + d] = f2bf(m[t]);
}

// ---------------- gemm3 + fused score ----------------
__global__ __launch_bounds__(256, 2)
void gemm3s(const u16* __restrict__ ps, const u16* __restrict__ tmax,
            const int* __restrict__ ids, const u16* __restrict__ Wf1b,
            const float* __restrict__ bf1, const float* __restrict__ w2,
            const float* __restrict__ mask, float* __restrict__ out) {
  int flat = blockIdx.x;
  int lid = (flat & 7) * 141 + (flat >> 3);
  int n = lid % 6;
  int m = (lid / 6) % 47;
  int b = lid / 282;

  const int m0 = m * 128;
  const int n0 = n * 128;
  const int tid = threadIdx.x;
  const int lane = tid & 63;
  const int wid = tid >> 6;
  const int wm = wid >> 1, wn = wid & 1;

  __shared__ u16 As[2][128 * 64];
  __shared__ u16 Bs[2][128 * 64];
  __shared__ int sids[100];
  __shared__ float pacc[4];
  if (tid < 100) sids[tid] = ids[b * 100 + tid];
  if (tid < 4) pacc[tid] = 0.f;
  __syncthreads();

  const u16* Abase = ps + (size_t)b * MPAD * DD;
  const u16* Tbase = tmax + (size_t)b * NUM_TABLES * 60 * DD;

  f32x4 acc[4][4] = {};

  const int lrow = lane >> 3;
  const int lcol_s = (((lane & 7) ^ (lrow & 7)) * 8);
  const int axor = (lane & 7) << 3;

  const u16* aptr[4];
  const u16* tptr[4];
  const u16* bptr[4];
#pragma unroll
  for (int j = 0; j < 4; ++j) {
    int row = m0 + wid * 32 + j * 8 + lrow;
    aptr[j] = Abase + (size_t)row * DD + lcol_s;
    int rp = row < 6000 ? row : 5999;
    int p = (unsigned)rp / 60u;
    int tok = rp - p * 60;
    int id = sids[p];
    tptr[j] = Tbase + ((size_t)(id * 60 + tok)) * DD + lcol_s;
    bptr[j] = Wf1b + (size_t)(n0 + wid * 32 + j * 8 + lrow) * 1536 + lcol_s;
  }

  // prologue: stage kt=0 into buf 0 (from ps)
#pragma unroll
  for (int j = 0; j < 4; ++j) {
    gload_lds16(aptr[j], &As[0][(wid * 32 + j * 8) * 64]);
    gload_lds16(bptr[j], &Bs[0][(wid * 32 + j * 8) * 64]);
    aptr[j] += 64; bptr[j] += 64;
  }
  __syncthreads();

  int cur = 0;
  for (int kt = 0; kt < 24; ++kt) {
    if (kt < 23) {
      if (kt + 1 == 12) {
#pragma unroll
        for (int j = 0; j < 4; ++j) aptr[j] = tptr[j];  // switch A source to tmax gather
      }
#pragma unroll
      for (int j = 0; j < 4; ++j) {
        gload_lds16(aptr[j], &As[cur ^ 1][(wid * 32 + j * 8) * 64]);
        gload_lds16(bptr[j], &Bs[cur ^ 1][(wid * 32 + j * 8) * 64]);
        aptr[j] += 64; bptr[j] += 64;
      }
    }

    bf16x8 af[2][4], bfr[2][4];
#pragma unroll
    for (int kf = 0; kf < 2; ++kf)
#pragma unroll
      for (int mf = 0; mf < 4; ++mf)
        af[kf][mf] = *(const bf16x8*)&As[cur][(wm * 64 + mf * 16 + (lane & 15)) * 64 + ((kf * 32 + (lane >> 4) * 8) ^ axor)];
#pragma unroll
    for (int kf = 0; kf < 2; ++kf)
#pragma unroll
      for (int nf = 0; nf < 4; ++nf)
        bfr[kf][nf] = *(const bf16x8*)&Bs[cur][(wn * 64 + nf * 16 + (lane & 15)) * 64 + ((kf * 32 + (lane >> 4) * 8) ^ axor)];

#pragma unroll
    for (int mf = 0; mf < 4; ++mf)
#pragma unroll
      for (int nf = 0; nf < 4; ++nf) {
        acc[mf][nf] = __builtin_amdgcn_mfma_f32_16x16x32_bf16(af[0][mf], bfr[0][nf], acc[mf][nf], 0, 0, 0);
        acc[mf][nf] = __builtin_amdgcn_mfma_f32_16x16x32_bf16(af[1][mf], bfr[1][nf], acc[mf][nf], 0, 0, 0);
      }
    __syncthreads();
    cur ^= 1;
  }

  // fused score epilogue
  float b1v[4], w2v[4];
#pragma unroll
  for (int nf = 0; nf < 4; ++nf) {
    int c = n0 + wn * 64 + nf * 16 + (lane & 15);
    b1v[nf] = bf1[c];
    w2v[nf] = w2[c];
  }
  const int pfirst = m0 / 60;
#pragma unroll
  for (int mf = 0; mf < 4; ++mf)
#pragma unroll
    for (int r = 0; r < 4; ++r) {
      int row = m0 + wm * 64 + mf * 16 + (lane >> 4) * 4 + r;
      float s = 0.f;
#pragma unroll
      for (int nf = 0; nf < 4; ++nf)
        s += fmaxf(acc[mf][nf][r] + b1v[nf], 0.f) * w2v[nf];
      s += __shfl_xor(s, 1);
      s += __shfl_xor(s, 2);
      s += __shfl_xor(s, 4);
      s += __shfl_xor(s, 8);
      if ((lane & 15) == 0 && row < 6000) {
        int p = (unsigned)row / 60u;
        int tok = row - p * 60;
        float mk = mask[((size_t)b * 100 + p) * 60 + tok];
        atomicAdd(&pacc[p - pfirst], mk * s);
      }
    }
  __syncthreads();
  int plast = (m0 + 127 < 6000 ? m0 + 127 : 5999) / 60;
  if (tid <= plast - pfirst)
    atomicAdd(out + b * 100 + pfirst + tid, pacc[tid]);
}

// ---------------- launch ----------------
extern "C" void kernel_launch(void* const* d_in, const int* in_sizes, int n_in,
                              void* d_out, int out_size, void* d_ws, size_t ws_size,
                              hipStream_t stream) {
  const float* answer = (const float*)d_in[0];
  const float* qps    = (const float*)d_in[1];
  const float* mask   = (const float*)d_in[2];
  const int*   tids   = (const int*)d_in[3];
  const float* Wp     = (const float*)d_in[4];
  const float* bp     = (const float*)d_in[5];
  const float* Wt     = (const float*)d_in[6];
  const float* bt     = (const float*)d_in[7];
  const float* Wf1    = (const float*)d_in[8];
  const float* bf1    = (const float*)d_in[9];
  const float* Wf2    = (const float*)d_in[10];
  const float* bf2    = (const float*)d_in[11];
  float* out = (float*)d_out;

  char* ws = (char*)d_ws;
  u16* Qpad = (u16*)(ws + 0);            // 36,962,304
  u16* ps   = (u16*)(ws + 36962304);     // 36,962,304
  u16* ts   = (u16*)(ws + 73924608);     // 36,962,304
  u16* Bcat = (u16*)(ws + 110886912);    // 9,437,184
  u16* Wf1b = (u16*)(ws + 120324096);    // 2,359,296
  float* cp = (float*)(ws + 122683392);  // 12,288
  float* ct = (float*)(ws + 122695680);  // 12,288
  u16* tmax = (u16*)(ws + 122707968);    // 3,686,400

  prep_all<<<13442, 256, 0, stream>>>(qps, (uint4*)Qpad, answer, Wp, Wt, Bcat,
                                      Wf1, (uint4*)Wf1b, bp, bt, cp, ct,
                                      mask, bf2, out);

  gemm12<<<2256, 256, 0, stream>>>(Qpad, Bcat, cp, ct, ps, ts);

  table_max_kernel<<<720, 256, 0, stream>>>(ts, tids, tmax);

  gemm3s<<<1128, 256, 0, stream>>>(ps, tmax, tids, Wf1b, bf1, Wf2, mask, out);
}